// Round 1
// baseline (148.367 us; speedup 1.0000x reference)
//
#include <hip/hip_runtime.h>
#include <hip/hip_fp16.h>
#include <math.h>

#define B_ 128
#define N_ 512
#define C_ 128
#define W_ 128
#define LDSW 136  // padded row stride (halves); b128 access = uniform bank spread

typedef _Float16 f16;
typedef _Float16 f16x8 __attribute__((ext_vector_type(8)));
typedef _Float16 f16x4 __attribute__((ext_vector_type(4)));
typedef float f32x4 __attribute__((ext_vector_type(4)));

#define MFMA16(a, b, c) __builtin_amdgcn_mfma_f32_16x16x32_f16(a, b, c, 0, 0, 0)

#define LOG2E 1.44269504f
#define MASKF (-1e-6f * LOG2E)  // faithful -1e-6 fill, log2 domain

// ---------------------------------------------------------------------------
// K0: transpose Wq/Wk/Wv (fp32 [C][W]) -> fp16 WT[w][c]. grid(3 mats, 8 slabs)
// ---------------------------------------------------------------------------
__global__ __launch_bounds__(256) void prep_w(const float* __restrict__ Wq,
                                              const float* __restrict__ Wk,
                                              const float* __restrict__ Wv,
                                              f16* __restrict__ wT) {
  __shared__ float xs[16 * 129];
  const float* src = blockIdx.x == 0 ? Wq : (blockIdx.x == 1 ? Wk : Wv);
  f16* dst = wT + (size_t)blockIdx.x * C_ * W_;
  const int c0 = blockIdx.y * 16;
  const int t = threadIdx.x;
  for (int ii = 0; ii < 2; ++ii) {
    int idx = t + 256 * ii;           // 512 float4 = 16 rows x 32
    int row = idx >> 5, w4 = idx & 31;
    float4 v = *reinterpret_cast<const float4*>(src + (c0 + row) * W_ + w4 * 4);
    xs[row * 129 + w4 * 4 + 0] = v.x;
    xs[row * 129 + w4 * 4 + 1] = v.y;
    xs[row * 129 + w4 * 4 + 2] = v.z;
    xs[row * 129 + w4 * 4 + 3] = v.w;
  }
  __syncthreads();
  int o = t * 8;
  int w = o >> 4, cc = o & 15;        // cc in {0,8}
  f16x8 h;
  for (int jj = 0; jj < 8; ++jj) h[jj] = (f16)xs[(cc + jj) * 129 + w];
  *reinterpret_cast<f16x8*>(dst + w * C_ + c0 + cc) = h;
}

// ---------------------------------------------------------------------------
// K1: fused QKV projection v6 = v5 + K-phase skip for fully-masked chunks
//     (K rows n with n0 > valid_len are never read by flash: boundary chunk
//      already covers rows up to ceil((vl+1)/128)*128-1).
// ---------------------------------------------------------------------------
__global__ __launch_bounds__(256, 2) void proj(const float* __restrict__ x,
                                               const float* __restrict__ bq,
                                               const float* __restrict__ bk,
                                               const float* __restrict__ bv,
                                               const f16* __restrict__ wT,
                                               const int* __restrict__ vlen,
                                               f16* __restrict__ q,
                                               f16* __restrict__ k,
                                               f16* __restrict__ vT) {
  __shared__ f16 wls[2][128 * LDSW];
  const int b = blockIdx.y, n0 = blockIdx.x * 128;
  const int t = threadIdx.x, wave = t >> 6, lane = t & 63;
  const int quad = lane >> 4, l15 = lane & 15;
  const int vl = vlen[b];
  const bool doK = (n0 <= vl);  // K rows of fully-masked chunks are dead

  float4 xr[2][4][2];
  for (int tile = 0; tile < 2; ++tile)
    for (int ks = 0; ks < 4; ++ks) {
      const float* p = x + ((size_t)(b * N_ + n0 + wave * 32 + tile * 16 +
                                     l15)) * C_ + ks * 32 + quad * 8;
      xr[tile][ks][0] = *reinterpret_cast<const float4*>(p);
      xr[tile][ks][1] = *reinterpret_cast<const float4*>(p + 4);
    }

  for (int i = 0; i < 8; ++i) {
    int idx = t + 256 * i;  // 2048 x 16B
    f16x8 tmp = *reinterpret_cast<const f16x8*>(wT + (size_t)idx * 8);
    *reinterpret_cast<f16x8*>(&wls[0][(idx >> 4) * LDSW + (idx & 15) * 8]) =
        tmp;
  }

  f16x8 af[2][4];
  for (int tile = 0; tile < 2; ++tile)
    for (int ks = 0; ks < 4; ++ks) {
      f16x8 h;
      h[0] = (f16)xr[tile][ks][0].x; h[1] = (f16)xr[tile][ks][0].y;
      h[2] = (f16)xr[tile][ks][0].z; h[3] = (f16)xr[tile][ks][0].w;
      h[4] = (f16)xr[tile][ks][1].x; h[5] = (f16)xr[tile][ks][1].y;
      h[6] = (f16)xr[tile][ks][1].z; h[7] = (f16)xr[tile][ks][1].w;
      af[tile][ks] = h;
    }
  __syncthreads();  // lds[0] ready

  for (int ph = 0; ph < 3; ++ph) {
    const f16* wl = wls[ph & 1];

    f16x8 wst[8];
    if (ph < 2)
      for (int i = 0; i < 8; ++i)
        wst[i] = *reinterpret_cast<const f16x8*>(
            wT + (size_t)(ph + 1) * 16384 + (size_t)(t + 256 * i) * 8);

    f32x4 acc[8][2];
    for (int ct = 0; ct < 8; ++ct) {
      acc[ct][0] = {0.f, 0.f, 0.f, 0.f};
      acc[ct][1] = {0.f, 0.f, 0.f, 0.f};
    }

    if (ph < 2) {
      if (ph == 0 || doK) {
        for (int ct = 0; ct < 8; ++ct) {
          f16x8 wf[4];
          for (int ks = 0; ks < 4; ++ks)
            wf[ks] = *reinterpret_cast<const f16x8*>(
                &wl[(ct * 16 + l15) * LDSW + ks * 32 + quad * 8]);
          for (int ks = 0; ks < 4; ++ks) {
            acc[ct][0] = MFMA16(wf[ks], af[0][ks], acc[ct][0]);
            acc[ct][1] = MFMA16(wf[ks], af[1][ks], acc[ct][1]);
          }
        }
        const float* bias = ph == 0 ? bq : bk;
        const float scale = ph == 0 ? LOG2E : 1.0f;
        f16* dst = ph == 0 ? q : k;
        for (int ct = 0; ct < 8; ++ct) {
          const float4 bb =
              *reinterpret_cast<const float4*>(bias + ct * 16 + quad * 4);
          for (int tile = 0; tile < 2; ++tile) {
            int n = n0 + wave * 32 + tile * 16 + l15;
            f16x4 h;
            h.x = (f16)((acc[ct][tile][0] + bb.x) * scale);
            h.y = (f16)((acc[ct][tile][1] + bb.y) * scale);
            h.z = (f16)((acc[ct][tile][2] + bb.z) * scale);
            h.w = (f16)((acc[ct][tile][3] + bb.w) * scale);
            *reinterpret_cast<f16x4*>(dst + ((size_t)(b * N_ + n)) * W_ +
                                      ct * 16 + quad * 4) = h;
          }
        }
      }
    } else {
      for (int ct = 0; ct < 8; ++ct) {
        f16x8 wf[4];
        for (int ks = 0; ks < 4; ++ks)
          wf[ks] = *reinterpret_cast<const f16x8*>(
              &wl[(ct * 16 + l15) * LDSW + ks * 32 + quad * 8]);
        for (int ks = 0; ks < 4; ++ks) {
          acc[ct][0] = MFMA16(af[0][ks], wf[ks], acc[ct][0]);
          acc[ct][1] = MFMA16(af[1][ks], wf[ks], acc[ct][1]);
        }
      }
      for (int ct = 0; ct < 8; ++ct) {
        int wcol = ct * 16 + l15;
        float bb = bv[wcol];
        for (int tile = 0; tile < 2; ++tile) {
          int n = n0 + wave * 32 + tile * 16 + quad * 4;
          f16x4 h;
          h.x = (f16)(acc[ct][tile][0] + bb);
          h.y = (f16)(acc[ct][tile][1] + bb);
          h.z = (f16)(acc[ct][tile][2] + bb);
          h.w = (f16)(acc[ct][tile][3] + bb);
          *reinterpret_cast<f16x4*>(&vT[((size_t)(b * W_ + wcol)) * N_ + n]) =
              h;
        }
      }
    }

    if (ph < 2) {
      for (int i = 0; i < 8; ++i) {
        int idx = t + 256 * i;
        *reinterpret_cast<f16x8*>(
            &wls[(ph + 1) & 1][(idx >> 4) * LDSW + (idx & 15) * 8]) = wst[i];
      }
      __syncthreads();
    }
  }
}

// ---------------------------------------------------------------------------
// K2: flash v8 = tail-skip restructure.
//     - 512 threads / 8 waves per WG; LDS inflated past 80KB -> exactly
//       1 WG/CU resident (same 8 waves/CU, 2/SIMD as v7), so the 512 WGs
//       queue in HW and variable-length items load-balance dynamically.
//     - Only nch = (vl>>7)+1 chunks run QK/softmax/PV. The fully-masked
//       tail (uniform score -1e-6) is a rank-1 closed form:
//         l += tailcnt*exp2(MASKF-m);  O += exp2(MASKF-m)*sum_tail(V)
//       with sum_tail(V) computed per-WG in fp32 from vT (L2-warm).
//     - Per wave: 16 m-cols for QK/softmax, 16 w-rows for PV; K staged
//       cooperatively in LDS with 1-chunk prefetch; 2 barriers/chunk.
// ---------------------------------------------------------------------------
__global__ __launch_bounds__(512, 2) void flash(const f16* __restrict__ q,
                                                const f16* __restrict__ k,
                                                const f16* __restrict__ vT,
                                                const int* __restrict__ vlen,
                                                float* __restrict__ out) {
  // 150-row declarations (128 used): total LDS 84.7KB > 80KB -> 1 WG/CU.
  __shared__ f16 kls[150 * LDSW];
  __shared__ f16 pls[150 * LDSW];
  __shared__ float bcast[128];
  __shared__ float vpart[512];
  __shared__ float vsum[128];
  const int b = blockIdx.x, m0 = blockIdx.y * 128;  // same-b WGs -> same XCD
  const int t = threadIdx.x, wave = t >> 6, lane = t & 63;
  const int quad = lane >> 4, l15 = lane & 15;
  const int vl = vlen[b];
  const int nch = (vl >> 7) + 1;        // chunks with any valid key: 1..4
  const int ntail0 = nch << 7;
  const int tailcnt = N_ - ntail0;      // fully-masked keys: {0,128,256,384}
  const int mcol = m0 + wave * 16;
  const int srow = t >> 4, sc16 = t & 15;  // staging coords (512 thr = 32 rows)

  // Q B-frags for this wave's 16 m-cols, held all kernel
  f16x8 qf[4];
  for (int kt = 0; kt < 4; ++kt)
    qf[kt] = *reinterpret_cast<const f16x8*>(
        q + ((size_t)(b * N_ + mcol + l15)) * W_ + kt * 32 + quad * 8);

  f32x4 oacc[8];  // [cm: all 128 m] x this wave's 16 w-rows
  for (int cm = 0; cm < 8; ++cm) oacc[cm] = {0.f, 0.f, 0.f, 0.f};
  float mrun = -3.4e38f, lrun = 0.f;

  // prologue: stage K(0) + tail-V partial sums
  for (int i = 0; i < 4; ++i) {
    int row = srow + 32 * i;
    *reinterpret_cast<f16x8*>(&kls[row * LDSW + sc16 * 8]) =
        *reinterpret_cast<const f16x8*>(k + ((size_t)(b * N_ + row)) * W_ +
                                        sc16 * 8);
  }
  if (tailcnt > 0) {
    int w = t & 127, g = t >> 7;        // 4 groups split the tail range
    int cnt = tailcnt >> 2;             // multiple of 32
    const f16* vp = vT + ((size_t)(b * W_ + w)) * N_ + ntail0 + g * cnt;
    float s = 0.f;
    for (int i = 0; i < cnt; i += 8) {
      f16x8 h = *reinterpret_cast<const f16x8*>(vp + i);
      for (int jj = 0; jj < 8; ++jj) s += (float)h[jj];
    }
    vpart[g * 128 + w] = s;
  }
  __syncthreads();  // bar1(0): kls(0) + vpart visible
  if (tailcnt > 0 && t < 128)
    vsum[t] = vpart[t] + vpart[128 + t] + vpart[256 + t] + vpart[384 + t];
  // vsum read only after later barriers (loop has >=2, nch>=1)

  for (int j = 0; j < nch; ++j) {
    const int n0 = j << 7;

    // V^T frags for this wave's 16 w-rows — issued at top, QK covers latency
    f16x8 vf[4];
    for (int kt = 0; kt < 4; ++kt)
      vf[kt] = *reinterpret_cast<const f16x8*>(
          vT + ((size_t)(b * W_ + wave * 16 + l15)) * N_ + n0 + kt * 32 +
          quad * 8);

    // K(j+1) prefetch (in flight across QK+softmax)
    f16x8 kst[4];
    if (j < nch - 1)
      for (int i = 0; i < 4; ++i)
        kst[i] = *reinterpret_cast<const f16x8*>(
            k + ((size_t)(b * N_ + n0 + 128 + srow + 32 * i)) * W_ + sc16 * 8);

    // QK: S^T slab (128 n x wave's 16 m)
    f32x4 sacc[8];
    for (int i = 0; i < 8; ++i) {
      sacc[i] = {0.f, 0.f, 0.f, 0.f};
      f16x8 kf[4];
      for (int kt = 0; kt < 4; ++kt)
        kf[kt] = *reinterpret_cast<const f16x8*>(
            &kls[(i * 16 + l15) * LDSW + kt * 32 + quad * 8]);
      for (int kt = 0; kt < 4; ++kt)
        sacc[i] = MFMA16(kf[kt], qf[kt], sacc[i]);
    }

    // mask (key index n = S^T row); only boundary chunk ever triggers
    for (int i = 0; i < 8; ++i)
      for (int r = 0; r < 4; ++r) {
        int n = n0 + 16 * i + quad * 4 + r;
        if (n > vl) sacc[i][r] = MASKF;
      }

    // wave-local online softmax (stats replicated across quads)
    float mx = -3.4e38f;
    for (int i = 0; i < 8; ++i)
      for (int r = 0; r < 4; ++r) mx = fmaxf(mx, sacc[i][r]);
    mx = fmaxf(mx, __shfl_xor(mx, 16));
    mx = fmaxf(mx, __shfl_xor(mx, 32));
    float mnew = fmaxf(mrun, mx);
    float alpha = exp2f(mrun - mnew);
    mrun = mnew;
    float s = 0.f;
    for (int i = 0; i < 8; ++i)
      for (int r = 0; r < 4; ++r) {
        float p = exp2f(sacc[i][r] - mnew);
        sacc[i][r] = p;
        s += p;
      }
    s += __shfl_xor(s, 16);
    s += __shfl_xor(s, 32);
    lrun = lrun * alpha + s;

    // write P^T slab (wave-own 16 m rows x 128 n) + alpha broadcast
    for (int i = 0; i < 8; ++i) {
      f16x4 h;
      h.x = (f16)sacc[i][0];
      h.y = (f16)sacc[i][1];
      h.z = (f16)sacc[i][2];
      h.w = (f16)sacc[i][3];
      *reinterpret_cast<f16x4*>(
          &pls[(wave * 16 + l15) * LDSW + 16 * i + quad * 4]) = h;
    }
    if (quad == 0) bcast[wave * 16 + l15] = alpha;
    __syncthreads();  // bar2: pls+bcast visible; all kls(j) reads done

    // write prefetched K(j+1) into kls (readers wait at loop-end barrier)
    if (j < nch - 1)
      for (int i = 0; i < 4; ++i)
        *reinterpret_cast<f16x8*>(&kls[(srow + 32 * i) * LDSW + sc16 * 8]) =
            kst[i];

    // rescale O by alpha of each m-col, then PV over all 128 m
    float al[8];
    for (int cm = 0; cm < 8; ++cm) al[cm] = bcast[cm * 16 + l15];
    for (int cm = 0; cm < 8; ++cm) oacc[cm] *= al[cm];
    for (int cm = 0; cm < 8; ++cm) {
      f16x8 pf[4];
      for (int kt = 0; kt < 4; ++kt)
        pf[kt] = *reinterpret_cast<const f16x8*>(
            &pls[(cm * 16 + l15) * LDSW + kt * 32 + quad * 8]);
      for (int kt = 0; kt < 4; ++kt)
        oacc[cm] = MFMA16(vf[kt], pf[kt], oacc[cm]);
    }
    __syncthreads();  // bar1(j+1): kls(j+1) visible; pls reads done
  }

  // closed-form tail: uniform weight exp2(MASKF - mfin) for tailcnt keys
  if (tailcnt > 0) {
    float mfin = fmaxf(mrun, MASKF);
    float at = exp2f(mrun - mfin);
    float pm = exp2f(MASKF - mfin);
    lrun = lrun * at + (float)tailcnt * pm;
    if (quad == 0) {
      vpart[wave * 16 + l15] = at;        // per-m rescale
      vpart[128 + wave * 16 + l15] = pm;  // per-m tail weight
    }
  }
  if (quad == 0) bcast[wave * 16 + l15] = 1.f / lrun;
  __syncthreads();

  if (tailcnt > 0) {
    const int w0 = wave * 16 + quad * 4;
    for (int cm = 0; cm < 8; ++cm) {
      float at = vpart[cm * 16 + l15];
      float pm = vpart[128 + cm * 16 + l15];
      for (int r = 0; r < 4; ++r)
        oacc[cm][r] = oacc[cm][r] * at + pm * vsum[w0 + r];
    }
  }

  // epilogue: scale by 1/l, store O[m][w] (float4, w contiguous)
  for (int cm = 0; cm < 8; ++cm) {
    float inv = bcast[cm * 16 + l15];
    int m = m0 + cm * 16 + l15;
    int w = wave * 16 + quad * 4;
    float4 o;
    o.x = oacc[cm][0] * inv;
    o.y = oacc[cm][1] * inv;
    o.z = oacc[cm][2] * inv;
    o.w = oacc[cm][3] * inv;
    *reinterpret_cast<float4*>(&out[((size_t)(b * N_ + m)) * W_ + w]) = o;
  }
}

// ---------------------------------------------------------------------------
extern "C" void kernel_launch(void* const* d_in, const int* in_sizes, int n_in,
                              void* d_out, int out_size, void* d_ws,
                              size_t ws_size, hipStream_t stream) {
  const float* x  = (const float*)d_in[0];
  const float* Wq = (const float*)d_in[1];
  const float* bq = (const float*)d_in[2];
  const float* Wk = (const float*)d_in[3];
  const float* bk = (const float*)d_in[4];
  const float* Wv = (const float*)d_in[5];
  const float* bv = (const float*)d_in[6];
  const int* vlen = (const int*)d_in[7];
  float* out = (float*)d_out;

  char* ws = (char*)d_ws;
  f16* wT = (f16*)ws;
  f16* q  = (f16*)(ws + (1u << 20));
  f16* k  = (f16*)(ws + (1u << 20) + (16u << 20));
  f16* vT = (f16*)(ws + (1u << 20) + (32u << 20));

  prep_w<<<dim3(3, 8), 256, 0, stream>>>(Wq, Wk, Wv, wT);
  proj<<<dim3(4, 128), 256, 0, stream>>>(x, bq, bk, bv, wT, vlen, q, k, vT);
  flash<<<dim3(128, 4), 512, 0, stream>>>(q, k, vT, vlen, out);
}